// Round 4
// baseline (184.119 us; speedup 1.0000x reference)
//
#include <hip/hip_runtime.h>
#include <hip/hip_bf16.h>

#define B_TOT 16384

typedef __attribute__((ext_vector_type(8))) short short8;
typedef __attribute__((ext_vector_type(4))) short short4v;
typedef __attribute__((ext_vector_type(4))) float f32x4;

__device__ __forceinline__ float bf2f(short s){
  unsigned u = ((unsigned)(unsigned short)s) << 16;
  return __uint_as_float(u);
}
__device__ __forceinline__ unsigned f2bfu(float f){
  __hip_bfloat16 h = __float2bfloat16(f);
  return (unsigned)*reinterpret_cast<unsigned short*>(&h);
}
__device__ __forceinline__ short f2bf(float f){
  __hip_bfloat16 h = __float2bfloat16(f);
  return *reinterpret_cast<short*>(&h);
}
// wave-internal LDS RAW fence (rule #18: lgkmcnt + sched_barrier)
__device__ __forceinline__ void wave_fence(){
  asm volatile("s_waitcnt lgkmcnt(0)" ::: "memory");
  __builtin_amdgcn_sched_barrier(0);
}

// ---- weight arena in d_ws (bf16 elements) ----
#define W_W1T   0        // [128][64]   enc_w1^T
#define W_W2T   8192     // [128][128]  enc_w2^T
#define W_GWT   24576    // [2][128][128] gat_w^T per head
#define W_HW1T  57344    // [256][256]  rows 0-127: val_w1^T, 128-255: pol_w1^T
#define W_PW2T  122880   // [8][128]    pol_w2^T
#define W_VW2   123904   // [128]       val_w2
#define W_TOTAL 124032

__global__ void prep_weights(const float* __restrict__ enc_w1, const float* __restrict__ enc_w2,
                             const float* __restrict__ gat_w, const float* __restrict__ val_w1,
                             const float* __restrict__ pol_w1, const float* __restrict__ pol_w2,
                             const float* __restrict__ val_w2, unsigned short* __restrict__ wt){
  int t = blockIdx.x*256 + threadIdx.x;
  if (t >= W_TOTAL) return;
  float v;
  if (t < 8192){ int c=t>>6, k=t&63; v = enc_w1[k*128 + c]; }
  else if (t < 24576){ int u=t-8192, c=u>>7, k=u&127; v = enc_w2[k*128 + c]; }
  else if (t < 57344){ int u=t-24576, h=u>>14, r=u&16383, c=r>>7, k=r&127; v = gat_w[h*16384 + k*128 + c]; }
  else if (t < 122880){ int u=t-57344, oc=u>>8, k=u&255; v = (oc<128) ? val_w1[k*128+oc] : pol_w1[k*128+(oc-128)]; }
  else if (t < 123904){ int u=t-122880, a=u>>7, k=u&127; v = pol_w2[k*8+a]; }
  else { int u=t-123904; v = val_w2[u]; }
  wt[t] = (unsigned short)f2bfu(v);
}

// ---- LDS arena (bytes) ----
// per-wave scratch: X [20][64] bf16 then h1/emb [20][128] bf16 (reads overflow to rows<32, harmless)
#define WSTR      5632
#define MISC_OFF  22528   // per-wave 256B: ej[20] f32, ei0[4] f32, adj[20] int
#define FINAL_OFF 23552   // [16][256] bf16 swz (8 KB)
#define LDS_TOT   31744   // H2 [16][256] bf16 aliases bytes [0,8192) after barrier 1

#define MFMA16(a,b,c) __builtin_amdgcn_mfma_f32_16x16x32_bf16(a,b,c,0,0,0)

__global__ __launch_bounds__(256, 2) void colight_main(
    const float* __restrict__ obs, const float* __restrict__ nobs, const int* __restrict__ adj,
    const float* __restrict__ enc_b1, const float* __restrict__ enc_b2,
    const float* __restrict__ gat_a,
    const float* __restrict__ val_b1, const float* __restrict__ val_b2,
    const float* __restrict__ pol_b1, const float* __restrict__ pol_b2,
    const unsigned short* __restrict__ wt_all,
    float* __restrict__ dout)
{
  __shared__ __align__(16) char lds[LDS_TOT];
  const int tid  = threadIdx.x;
  const int lane = tid & 63;
  const int wv   = tid >> 6;
  const int lm   = lane & 15;
  const int grp  = lane >> 4;
  const int kb   = grp * 8;
  const int gblk = blockIdx.x * 16;       // block agent base
  const int gw   = gblk + wv*4;           // wave agent base (4 agents/wave)

  char* ws = lds + wv*WSTR;
  float* ejL  = reinterpret_cast<float*>(lds + MISC_OFF + wv*256);
  float* ei0L = ejL + 20;
  int*   adjL = reinterpret_cast<int*>(ejL + 24);

  const unsigned short* w1t  = wt_all + W_W1T;
  const unsigned short* w2t  = wt_all + W_W2T;
  const unsigned short* gwt  = wt_all + W_GWT;
  const unsigned short* hw1t = wt_all + W_HW1T;
  const unsigned short* pw2t = wt_all + W_PW2T;
  const unsigned short* vw2  = wt_all + W_VW2;

  // ================= per-wave independent phase (no __syncthreads) =================

  // ---- stage adj + X (20 rows x 64) bf16, swizzled ----
  if (lane < 20) adjL[lane] = adj[(gw + lane/5)*5 + (lane%5)];
  #pragma unroll
  for (int i = 0; i < 5; ++i){
    int chunk = i*64 + lane;              // 320 = 20 rows x 16 float4
    int row = chunk >> 4;
    int c4  = (chunk & 15) * 4;
    int a = row/5, n = row%5;
    const float* src = n ? (nobs + ((gw+a)*4 + (n-1))*64 + c4)
                         : (obs  + (gw+a)*64 + c4);
    float4 v = *reinterpret_cast<const float4*>(src);
    short4v p = { f2bf(v.x), f2bf(v.y), f2bf(v.z), f2bf(v.w) };
    *reinterpret_cast<short4v*>(ws + ((row*128 + c4*2) ^ ((row & 7) << 4))) = p;
  }
  wave_fence();

  f32x4 acc[2][8];

  // ---- enc layer 1: X(32x64) @ w1t -> h1 (relu + b1) ----
  #pragma unroll
  for (int mt=0; mt<2; ++mt)
    #pragma unroll
    for (int nt=0; nt<8; ++nt) acc[mt][nt] = (f32x4){0.f,0.f,0.f,0.f};
  #pragma unroll
  for (int ks=0; ks<2; ++ks){
    short8 xa0 = *reinterpret_cast<short8*>(ws + (((lm   )*128 + (ks*32+kb)*2) ^ ((lm&7)<<4)));
    short8 xa1 = *reinterpret_cast<short8*>(ws + (((16+lm)*128 + (ks*32+kb)*2) ^ ((lm&7)<<4)));
    #pragma unroll
    for (int nt=0; nt<8; ++nt){
      short8 b = *reinterpret_cast<const short8*>(w1t + (nt*16+lm)*64 + ks*32 + kb);
      acc[0][nt] = MFMA16(xa0, b, acc[0][nt]);
      acc[1][nt] = MFMA16(xa1, b, acc[1][nt]);
    }
  }
  {
    float bv[8];
    #pragma unroll
    for (int nt=0; nt<8; ++nt) bv[nt] = enc_b1[nt*16+lm];
    wave_fence();            // X reads done before overwrite
    #pragma unroll
    for (int mt=0; mt<2; ++mt)
      #pragma unroll
      for (int nt=0; nt<8; ++nt)
        #pragma unroll
        for (int j=0; j<4; ++j){
          int row = mt*16 + grp*4 + j;
          if (row < 20)
            *reinterpret_cast<short*>(ws + ((row*256 + (nt*16+lm)*2) ^ ((row&7)<<4)))
              = f2bf(fmaxf(acc[mt][nt][j] + bv[nt], 0.f));
        }
  }
  wave_fence();

  // ---- enc layer 2: h1 @ w2t + b2 -> emb ----
  #pragma unroll
  for (int mt=0; mt<2; ++mt)
    #pragma unroll
    for (int nt=0; nt<8; ++nt) acc[mt][nt] = (f32x4){0.f,0.f,0.f,0.f};
  #pragma unroll
  for (int kf=0; kf<4; ++kf){
    short8 ha0 = *reinterpret_cast<short8*>(ws + (((lm   )*256 + (kf*32+kb)*2) ^ ((lm&7)<<4)));
    short8 ha1 = *reinterpret_cast<short8*>(ws + (((16+lm)*256 + (kf*32+kb)*2) ^ ((lm&7)<<4)));
    #pragma unroll
    for (int nt=0; nt<8; ++nt){
      short8 b = *reinterpret_cast<const short8*>(w2t + (nt*16+lm)*128 + kf*32 + kb);
      acc[0][nt] = MFMA16(ha0, b, acc[0][nt]);
      acc[1][nt] = MFMA16(ha1, b, acc[1][nt]);
    }
  }
  {
    float bv[8];
    #pragma unroll
    for (int nt=0; nt<8; ++nt) bv[nt] = enc_b2[nt*16+lm];
    wave_fence();            // h1 reads done before overwrite
    #pragma unroll
    for (int mt=0; mt<2; ++mt)
      #pragma unroll
      for (int nt=0; nt<8; ++nt)
        #pragma unroll
        for (int j=0; j<4; ++j){
          int row = mt*16 + grp*4 + j;
          if (row < 20)
            *reinterpret_cast<short*>(ws + ((row*256 + (nt*16+lm)*2) ^ ((row&7)<<4)))
              = f2bf(acc[mt][nt][j] + bv[nt]);
        }
  }
  wave_fence();

  // ---- GAT: 2 heads, Wh in registers, dots/softmax/combine in-wave ----
  unsigned fin[2][4][4];     // [head][agent][nt-pair] packed bf16x2 of final
  #pragma unroll
  for (int h=0; h<2; ++h){
    #pragma unroll
    for (int mt=0; mt<2; ++mt)
      #pragma unroll
      for (int nt=0; nt<8; ++nt) acc[mt][nt] = (f32x4){0.f,0.f,0.f,0.f};
    #pragma unroll
    for (int kf=0; kf<4; ++kf){
      short8 ea0 = *reinterpret_cast<short8*>(ws + (((lm   )*256 + (kf*32+kb)*2) ^ ((lm&7)<<4)));
      short8 ea1 = *reinterpret_cast<short8*>(ws + (((16+lm)*256 + (kf*32+kb)*2) ^ ((lm&7)<<4)));
      #pragma unroll
      for (int nt=0; nt<8; ++nt){
        short8 b = *reinterpret_cast<const short8*>(gwt + h*16384 + (nt*16+lm)*128 + kf*32 + kb);
        acc[0][nt] = MFMA16(ea0, b, acc[0][nt]);
        acc[1][nt] = MFMA16(ea1, b, acc[1][nt]);
      }
    }
    // dots: ej (a2) for all rows, ei (a1) for node-0 rows, from f32 accs
    {
      float a1v[8], a2v[8];
      #pragma unroll
      for (int nt=0; nt<8; ++nt){
        a1v[nt] = gat_a[h*256 + nt*16 + lm];
        a2v[nt] = gat_a[h*256 + 128 + nt*16 + lm];
      }
      #pragma unroll
      for (int mt=0; mt<2; ++mt)
        #pragma unroll
        for (int j=0; j<4; ++j){
          float s1 = 0.f, s2 = 0.f;
          #pragma unroll
          for (int nt=0; nt<8; ++nt){ s1 += acc[mt][nt][j]*a1v[nt]; s2 += acc[mt][nt][j]*a2v[nt]; }
          s1 += __shfl_xor(s1,1); s1 += __shfl_xor(s1,2); s1 += __shfl_xor(s1,4); s1 += __shfl_xor(s1,8);
          s2 += __shfl_xor(s2,1); s2 += __shfl_xor(s2,2); s2 += __shfl_xor(s2,4); s2 += __shfl_xor(s2,8);
          int row = mt*16 + grp*4 + j;
          if (lm == 0 && row < 20){
            ejL[row] = s2;
            if (row % 5 == 0) ei0L[row/5] = s1;
          }
        }
    }
    wave_fence();
    // masked softmax over 5 neighbors (replicated: a = lane&3)
    float att[5];
    {
      int a_ = lane & 3;
      float e0 = ei0L[a_];
      int msk[5]; float mx = -1e30f;
      #pragma unroll
      for (int n=0; n<5; ++n){
        msk[n] = adjL[a_*5 + n];
        float s = e0 + ejL[a_*5 + n];
        s = (s > 0.f) ? s : 0.2f*s;
        att[n] = s;
        if (msk[n] && s > mx) mx = s;
      }
      float den = 0.f;
      #pragma unroll
      for (int n=0; n<5; ++n){
        float e = msk[n] ? __expf(att[n]-mx) : 0.f;
        att[n] = e; den += e;
      }
      float inv = 1.f/den;
      #pragma unroll
      for (int n=0; n<5; ++n) att[n] *= inv;
    }
    // combine: final[ag][c] = sum_n att[ag][n] * Wh[5ag+n][c]  (rows 0..19 only -> no garbage)
    #pragma unroll
    for (int ag=0; ag<4; ++ag){
      float s[8];
      #pragma unroll
      for (int nt=0; nt<8; ++nt) s[nt] = 0.f;
      #pragma unroll
      for (int n=0; n<5; ++n){
        const int r = ag*5 + n, mt = r >> 4, g2 = (r >> 2) & 3, j = r & 3;
        float wn = __shfl(att[n], ag);
        #pragma unroll
        for (int nt=0; nt<8; ++nt){
          float t = (grp == g2) ? wn*acc[mt][nt][j] : 0.f;
          s[nt] += t;
        }
      }
      #pragma unroll
      for (int nt=0; nt<8; ++nt){ s[nt] += __shfl_xor(s[nt],16); s[nt] += __shfl_xor(s[nt],32); }
      #pragma unroll
      for (int p=0; p<4; ++p)
        fin[h][ag][p] = f2bfu(s[2*p]) | (f2bfu(s[2*p+1]) << 16);
    }
  }

  // ---- write FINAL [16][256] bf16 swz (lanes 0-31: grp0 -> head0, grp1 -> head1) ----
  if (lane < 32){
    #pragma unroll
    for (int ag=0; ag<4; ++ag)
      #pragma unroll
      for (int p=0; p<4; ++p){
        unsigned v = (lane < 16) ? fin[0][ag][p] : fin[1][ag][p];
        int rowA = wv*4 + ag;
        int c0 = ((lane < 16) ? 0 : 128) + 2*p*16 + lm;
        *reinterpret_cast<short*>(lds + FINAL_OFF + ((rowA*512 + c0*2) ^ ((rowA&7)<<4)))
            = (short)(v & 0xffff);
        *reinterpret_cast<short*>(lds + FINAL_OFF + ((rowA*512 + (c0+16)*2) ^ ((rowA&7)<<4)))
            = (short)(v >> 16);
      }
  }
  __syncthreads();

  // ================= block-cooperative tail =================

  // ---- heads hidden: FINAL(16x256) @ hw1t -> H2 (16x256) relu, wave w owns cols [64w,64w+64) ----
  {
    short8 fa[8];
    #pragma unroll
    for (int kf=0; kf<8; ++kf)
      fa[kf] = *reinterpret_cast<short8*>(lds + FINAL_OFF + ((lm*512 + (kf*32+kb)*2) ^ ((lm&7)<<4)));
    f32x4 hacc[4];
    #pragma unroll
    for (int nt=0; nt<4; ++nt) hacc[nt] = (f32x4){0.f,0.f,0.f,0.f};
    #pragma unroll
    for (int kf=0; kf<8; ++kf)
      #pragma unroll
      for (int nt=0; nt<4; ++nt){
        short8 b = *reinterpret_cast<const short8*>(hw1t + (wv*64 + nt*16+lm)*256 + kf*32 + kb);
        hacc[nt] = MFMA16(fa[kf], b, hacc[nt]);
      }
    #pragma unroll
    for (int nt=0; nt<4; ++nt){
      int oc = wv*64 + nt*16 + lm;
      float bv = (oc < 128) ? val_b1[oc] : pol_b1[oc-128];
      #pragma unroll
      for (int j=0; j<4; ++j){
        int row = grp*4 + j;
        *reinterpret_cast<short*>(lds + ((row*512 + oc*2) ^ ((row&7)<<4)))
            = f2bf(fmaxf(hacc[nt][j] + bv, 0.f));
      }
    }
  }
  __syncthreads();

  // ---- final projections from H2 (lds base 0) ----
  if (tid < 128){
    int a = tid >> 3, act = tid & 7;
    float s = pol_b2[act];
    #pragma unroll
    for (int i=0; i<16; ++i){
      short8 v = *reinterpret_cast<short8*>(lds + ((a*512 + (128 + i*8)*2) ^ ((a&7)<<4)));
      short8 w = *reinterpret_cast<const short8*>(pw2t + act*128 + i*8);
      #pragma unroll
      for (int e=0; e<8; ++e) s += bf2f(v[e]) * bf2f(w[e]);
    }
    dout[B_TOT + (gblk + a)*8 + act] = s;
  } else if (tid < 160){
    int q = tid - 128, a = q >> 1, hf = q & 1;
    float s = 0.f;
    #pragma unroll
    for (int i=0; i<8; ++i){
      short8 v = *reinterpret_cast<short8*>(lds + ((a*512 + (hf*64 + i*8)*2) ^ ((a&7)<<4)));
      short8 w = *reinterpret_cast<const short8*>(vw2 + hf*64 + i*8);
      #pragma unroll
      for (int e=0; e<8; ++e) s += bf2f(v[e]) * bf2f(w[e]);
    }
    s += __shfl_xor(s, 1);
    if (!hf) dout[gblk + a] = s + val_b2[0];
  }
}

extern "C" void kernel_launch(void* const* d_in, const int* in_sizes, int n_in,
                              void* d_out, int out_size, void* d_ws, size_t ws_size,
                              hipStream_t stream) {
  (void)in_sizes; (void)n_in; (void)out_size; (void)ws_size;
  const float* obs    = (const float*)d_in[0];
  const float* nobs   = (const float*)d_in[1];
  const int*   adj    = (const int*)  d_in[2];
  const float* enc_w1 = (const float*)d_in[3];
  const float* enc_b1 = (const float*)d_in[4];
  const float* enc_w2 = (const float*)d_in[5];
  const float* enc_b2 = (const float*)d_in[6];
  const float* gat_w  = (const float*)d_in[7];
  const float* gat_a  = (const float*)d_in[8];
  const float* val_w1 = (const float*)d_in[9];
  const float* val_b1 = (const float*)d_in[10];
  const float* val_w2 = (const float*)d_in[11];
  const float* val_b2 = (const float*)d_in[12];
  const float* pol_w1 = (const float*)d_in[13];
  const float* pol_b1 = (const float*)d_in[14];
  const float* pol_w2 = (const float*)d_in[15];
  const float* pol_b2 = (const float*)d_in[16];

  unsigned short* wt = (unsigned short*)d_ws;

  prep_weights<<<(W_TOTAL+255)/256, 256, 0, stream>>>(enc_w1, enc_w2, gat_w, val_w1, pol_w1,
                                                      pol_w2, val_w2, wt);

  colight_main<<<B_TOT/16, 256, 0, stream>>>(
      obs, nobs, adj, enc_b1, enc_b2, gat_a,
      val_b1, val_b2, pol_b1, pol_b2,
      wt, (float*)d_out);
}

// Round 5
// 131.927 us; speedup vs baseline: 1.3956x; 1.3956x over previous
//
#include <hip/hip_runtime.h>
#include <hip/hip_bf16.h>

#define B_TOT 16384

typedef __attribute__((ext_vector_type(8))) short short8;
typedef __attribute__((ext_vector_type(4))) short short4v;
typedef __attribute__((ext_vector_type(4))) float f32x4;

__device__ __forceinline__ float bf2f(short s){
  unsigned u = ((unsigned)(unsigned short)s) << 16;
  return __uint_as_float(u);
}
__device__ __forceinline__ short f2bf(float f){
  __hip_bfloat16 h = __float2bfloat16(f);
  return *reinterpret_cast<short*>(&h);
}

#define MFMA16(a,b,c) __builtin_amdgcn_mfma_f32_16x16x32_bf16(a,b,c,0,0,0)

// ---- d_ws layout ----
// bf16 elements:
#define W_W1T   0        // [128][64]   enc_w1^T  [oc][k]
#define W_W2T   8192     // [128][128]  enc_w2^T
#define W_GWT   24576    // [2][128][128] gat_w^T per head: [h][o][d]
#define W_HW1T  57344    // [256][256]  rows 0-127 val_w1^T, 128-255 pol_w1^T
#define W_PW2T  122880   // [8][128]    pol_w2^T
#define W_VW2   123904   // [128]       val_w2
#define W_NELEM 124032
// bytes:
#define CVEC_BYTE 248064 // [4][128] f32: [2h+0]=gat_w@a1 (ei), [2h+1]=gat_w@a2 (ej)
#define MIX_BYTE  250112 // [16384][256] bf16 (mix, head-major)
#define PREP_TOT  124544 // prep thread count (weights + 512 cvec dots)

__global__ void prep_weights(const float* __restrict__ enc_w1, const float* __restrict__ enc_w2,
                             const float* __restrict__ gat_w, const float* __restrict__ gat_a,
                             const float* __restrict__ val_w1, const float* __restrict__ pol_w1,
                             const float* __restrict__ pol_w2, const float* __restrict__ val_w2,
                             unsigned short* __restrict__ wt, float* __restrict__ cvec){
  int t = blockIdx.x*256 + threadIdx.x;
  if (t < W_NELEM){
    float v;
    if (t < 8192){ int c=t>>6, k=t&63; v = enc_w1[k*128 + c]; }
    else if (t < 24576){ int u=t-8192, c=u>>7, k=u&127; v = enc_w2[k*128 + c]; }
    else if (t < 57344){ int u=t-24576, h=u>>14, r=u&16383, c=r>>7, k=r&127; v = gat_w[h*16384 + k*128 + c]; }
    else if (t < 122880){ int u=t-57344, oc=u>>8, k=u&255; v = (oc<128) ? val_w1[k*128+oc] : pol_w1[k*128+(oc-128)]; }
    else if (t < 123904){ int u=t-122880, a=u>>7, k=u&127; v = pol_w2[k*8+a]; }
    else { int u=t-123904; v = val_w2[u]; }
    wt[t] = (unsigned short)(unsigned)*reinterpret_cast<unsigned short*>(&(__hip_bfloat16&)(*(__hip_bfloat16*)&v)); // placeholder
  } else if (t < PREP_TOT){
    int q = t - W_NELEM;
    int vsel = q >> 7, d = q & 127;
    int h = vsel >> 1, s2 = vsel & 1;
    const float* gw = gat_w + h*16384 + d*128;
    const float* aa = gat_a + h*256 + s2*128;
    float s = 0.f;
    for (int o=0;o<128;++o) s += gw[o]*aa[o];
    cvec[vsel*128 + d] = s;
  }
}

// fix the placeholder hack above with a clean second definition path:
// (we keep prep simple: recompute bf16 conversion properly)
__global__ void prep_weights2(const float* __restrict__ enc_w1, const float* __restrict__ enc_w2,
                              const float* __restrict__ gat_w, const float* __restrict__ gat_a,
                              const float* __restrict__ val_w1, const float* __restrict__ pol_w1,
                              const float* __restrict__ pol_w2, const float* __restrict__ val_w2,
                              unsigned short* __restrict__ wt, float* __restrict__ cvec){
  int t = blockIdx.x*256 + threadIdx.x;
  if (t < W_NELEM){
    float v;
    if (t < 8192){ int c=t>>6, k=t&63; v = enc_w1[k*128 + c]; }
    else if (t < 24576){ int u=t-8192, c=u>>7, k=u&127; v = enc_w2[k*128 + c]; }
    else if (t < 57344){ int u=t-24576, h=u>>14, r=u&16383, c=r>>7, k=r&127; v = gat_w[h*16384 + k*128 + c]; }
    else if (t < 122880){ int u=t-57344, oc=u>>8, k=u&255; v = (oc<128) ? val_w1[k*128+oc] : pol_w1[k*128+(oc-128)]; }
    else if (t < 123904){ int u=t-122880, a=u>>7, k=u&127; v = pol_w2[k*8+a]; }
    else { int u=t-123904; v = val_w2[u]; }
    short b = f2bf(v);
    wt[t] = (unsigned short)b;
  } else if (t < PREP_TOT){
    int q = t - W_NELEM;
    int vsel = q >> 7, d = q & 127;
    int h = vsel >> 1, s2 = vsel & 1;
    const float* gw = gat_w + h*16384 + d*128;
    const float* aa = gat_a + h*256 + s2*128;
    float s = 0.f;
    for (int o=0;o<128;++o) s += gw[o]*aa[o];
    cvec[vsel*128 + d] = s;
  }
}

// ============ K1: encoder + attention + mix (16 agents / block) ============
// LDS: X [80][64] bf16 swz @0 (10240); h1 [80][128] bf16 swz @10240 (20480);
// emb [80][128] bf16 swz @0 after GEMM2 (overwrites X + low h1 rows, barrier-guarded)
#define K1_LDS 30720

__global__ __launch_bounds__(256, 2) void enc_gat(
    const float* __restrict__ obs, const float* __restrict__ nobs, const int* __restrict__ adjp,
    const float* __restrict__ enc_b1, const float* __restrict__ enc_b2,
    const unsigned short* __restrict__ wt_all, const float* __restrict__ cvec,
    unsigned short* __restrict__ mixws)
{
  __shared__ __align__(16) char lds[K1_LDS];
  const int tid  = threadIdx.x;
  const int lane = tid & 63;
  const int wv   = tid >> 6;
  const int lm   = lane & 15;
  const int grp  = lane >> 4;
  const int kb   = grp * 8;
  const int gblk = blockIdx.x * 16;

  const unsigned short* w1t = wt_all + W_W1T;
  const unsigned short* w2t = wt_all + W_W2T;

  // ---- stage X (80 x 64) f32 -> bf16 swz ----
  #pragma unroll
  for (int i = 0; i < 5; ++i){
    int chunk = i*256 + tid;            // 1280 float4 chunks
    int row = chunk >> 4;
    int c4  = (chunk & 15) * 4;
    int a = row/5, n = row%5;
    const float* src = n ? (nobs + ((size_t)(gblk+a)*4 + (n-1))*64 + c4)
                         : (obs  + (size_t)(gblk+a)*64 + c4);
    float4 v = *reinterpret_cast<const float4*>(src);
    short4v p = { f2bf(v.x), f2bf(v.y), f2bf(v.z), f2bf(v.w) };
    *reinterpret_cast<short4v*>(lds + ((row*128 + c4*2) ^ ((row & 7) << 4))) = p;
  }
  __syncthreads();

  const int c0 = wv*32 + lm, c1 = c0 + 16;

  // ---- GEMM1: X @ w1t -> h1 (relu+b1), wave owns cols [32w,32w+32) ----
  f32x4 acc[5][2];
  #pragma unroll
  for (int mt=0; mt<5; ++mt){ acc[mt][0]=(f32x4){0,0,0,0}; acc[mt][1]=(f32x4){0,0,0,0}; }
  #pragma unroll
  for (int ks=0; ks<2; ++ks){
    short8 b0 = *reinterpret_cast<const short8*>(w1t + c0*64 + ks*32 + kb);
    short8 b1 = *reinterpret_cast<const short8*>(w1t + c1*64 + ks*32 + kb);
    #pragma unroll
    for (int mt=0; mt<5; ++mt){
      int row = mt*16 + lm;
      short8 a = *reinterpret_cast<short8*>(lds + ((row*128 + (ks*32+kb)*2) ^ ((row&7)<<4)));
      acc[mt][0] = MFMA16(a, b0, acc[mt][0]);
      acc[mt][1] = MFMA16(a, b1, acc[mt][1]);
    }
  }
  {
    float bv0 = enc_b1[c0], bv1 = enc_b1[c1];
    #pragma unroll
    for (int mt=0; mt<5; ++mt)
      #pragma unroll
      for (int j=0; j<4; ++j){
        int row = mt*16 + grp*4 + j;
        *reinterpret_cast<short*>(lds + 10240 + ((row*256 + c0*2) ^ ((row&7)<<4)))
            = f2bf(fmaxf(acc[mt][0][j] + bv0, 0.f));
        *reinterpret_cast<short*>(lds + 10240 + ((row*256 + c1*2) ^ ((row&7)<<4)))
            = f2bf(fmaxf(acc[mt][1][j] + bv1, 0.f));
      }
  }
  __syncthreads();

  // ---- GEMM2: h1 @ w2t + b2 -> emb (kept in acc) ----
  f32x4 acc2[5][2];
  #pragma unroll
  for (int mt=0; mt<5; ++mt){ acc2[mt][0]=(f32x4){0,0,0,0}; acc2[mt][1]=(f32x4){0,0,0,0}; }
  #pragma unroll
  for (int ks=0; ks<4; ++ks){
    short8 b0 = *reinterpret_cast<const short8*>(w2t + c0*128 + ks*32 + kb);
    short8 b1 = *reinterpret_cast<const short8*>(w2t + c1*128 + ks*32 + kb);
    #pragma unroll
    for (int mt=0; mt<5; ++mt){
      int row = mt*16 + lm;
      short8 a = *reinterpret_cast<short8*>(lds + 10240 + ((row*256 + (ks*32+kb)*2) ^ ((row&7)<<4)));
      acc2[mt][0] = MFMA16(a, b0, acc2[mt][0]);
      acc2[mt][1] = MFMA16(a, b1, acc2[mt][1]);
    }
  }
  __syncthreads();   // all h1 reads done; emb may overwrite [0,20480)
  {
    float b20 = enc_b2[c0], b21 = enc_b2[c1];
    #pragma unroll
    for (int mt=0; mt<5; ++mt)
      #pragma unroll
      for (int j=0; j<4; ++j){
        int row = mt*16 + grp*4 + j;
        *reinterpret_cast<short*>(lds + ((row*256 + c0*2) ^ ((row&7)<<4)))
            = f2bf(acc2[mt][0][j] + b20);
        *reinterpret_cast<short*>(lds + ((row*256 + c1*2) ^ ((row&7)<<4)))
            = f2bf(acc2[mt][1][j] + b21);
      }
  }
  __syncthreads();

  // ---- attention + mix: one agent per 16-lane group ----
  const int ag = wv*4 + grp;           // 0..15
  const int ga = gblk + ag;
  float ef[5][8];
  #pragma unroll
  for (int n=0; n<5; ++n){
    int row = ag*5 + n;
    short8 er = *reinterpret_cast<short8*>(lds + ((row*256 + lm*16) ^ ((row&7)<<4)));
    #pragma unroll
    for (int e=0; e<8; ++e) ef[n][e] = bf2f(er[e]);
  }
  int msk[5];
  #pragma unroll
  for (int n=0; n<5; ++n) msk[n] = adjp[(size_t)ga*5 + n];

  #pragma unroll
  for (int h=0; h<2; ++h){
    float c1v[8], c2v[8];
    #pragma unroll
    for (int e=0; e<8; ++e){
      c1v[e] = cvec[(2*h  )*128 + lm*8 + e];
      c2v[e] = cvec[(2*h+1)*128 + lm*8 + e];
    }
    float ei = 0.f;
    #pragma unroll
    for (int e=0; e<8; ++e) ei += ef[0][e]*c1v[e];
    ei += __shfl_xor(ei,1); ei += __shfl_xor(ei,2); ei += __shfl_xor(ei,4); ei += __shfl_xor(ei,8);

    float at[5]; float mx = -1e30f;
    #pragma unroll
    for (int n=0; n<5; ++n){
      float t = 0.f;
      #pragma unroll
      for (int e=0; e<8; ++e) t += ef[n][e]*c2v[e];
      t += __shfl_xor(t,1); t += __shfl_xor(t,2); t += __shfl_xor(t,4); t += __shfl_xor(t,8);
      float s = ei + t;
      s = (s > 0.f) ? s : 0.2f*s;
      at[n] = s;
      if (msk[n] && s > mx) mx = s;
    }
    float den = 0.f;
    #pragma unroll
    for (int n=0; n<5; ++n){
      float e2 = msk[n] ? __expf(at[n]-mx) : 0.f;
      at[n] = e2; den += e2;
    }
    float inv = 1.f/den;
    short8 o;
    #pragma unroll
    for (int e=0; e<8; ++e){
      float s = 0.f;
      #pragma unroll
      for (int n=0; n<5; ++n) s += at[n]*ef[n][e];
      o[e] = f2bf(s*inv);
    }
    *reinterpret_cast<short8*>(mixws + (size_t)ga*256 + h*128 + lm*8) = o;
  }
}

// ============ K2: tail (32 agents / block) ============
// LDS: mixT [32][256] swz @0 (16KB); final [32][256] swz @16384 (16KB); H2 [32][256] @0
#define T_LDS 32768

__global__ __launch_bounds__(256, 2) void tail_k(
    const unsigned short* __restrict__ mixws, const unsigned short* __restrict__ wt_all,
    const float* __restrict__ val_b1, const float* __restrict__ val_b2,
    const float* __restrict__ pol_b1, const float* __restrict__ pol_b2,
    float* __restrict__ dout)
{
  __shared__ __align__(16) char lds[T_LDS];
  const int tid  = threadIdx.x;
  const int lane = tid & 63;
  const int wv   = tid >> 6;
  const int lm   = lane & 15;
  const int grp  = lane >> 4;
  const int kb   = grp * 8;
  const int gb   = blockIdx.x * 32;

  const unsigned short* gwt  = wt_all + W_GWT;
  const unsigned short* hw1t = wt_all + W_HW1T;
  const unsigned short* pw2t = wt_all + W_PW2T;
  const unsigned short* vw2  = wt_all + W_VW2;

  // ---- stage mix (32 x 256) ----
  #pragma unroll
  for (int i=0; i<4; ++i){
    int chunk = i*256 + tid;            // 1024 short8 chunks
    int row = chunk >> 5;
    int c8  = (chunk & 31) * 8;
    short8 v = *reinterpret_cast<const short8*>(mixws + (size_t)(gb+row)*256 + c8);
    *reinterpret_cast<short8*>(lds + ((row*512 + c8*2) ^ ((row&7)<<4))) = v;
  }
  __syncthreads();

  // ---- mix-GEMM: final[., h*128+o] = mix[., h*128+:] @ gat_w[h]^T ----
  const int hh = wv >> 1, half = wv & 1;
  f32x4 fac[2][4];
  #pragma unroll
  for (int mt=0; mt<2; ++mt)
    #pragma unroll
    for (int nt=0; nt<4; ++nt) fac[mt][nt] = (f32x4){0,0,0,0};
  #pragma unroll
  for (int ks=0; ks<4; ++ks){
    short8 a0 = *reinterpret_cast<short8*>(lds + (((lm   )*512 + (hh*128+ks*32+kb)*2) ^ ((lm&7)<<4)));
    short8 a1 = *reinterpret_cast<short8*>(lds + (((16+lm)*512 + (hh*128+ks*32+kb)*2) ^ ((lm&7)<<4)));
    #pragma unroll
    for (int nt=0; nt<4; ++nt){
      short8 b = *reinterpret_cast<const short8*>(gwt + hh*16384 + (half*64+nt*16+lm)*128 + ks*32 + kb);
      fac[0][nt] = MFMA16(a0, b, fac[0][nt]);
      fac[1][nt] = MFMA16(a1, b, fac[1][nt]);
    }
  }
  #pragma unroll
  for (int mt=0; mt<2; ++mt)
    #pragma unroll
    for (int nt=0; nt<4; ++nt)
      #pragma unroll
      for (int j=0; j<4; ++j){
        int row = mt*16 + grp*4 + j;
        int col = hh*128 + half*64 + nt*16 + lm;
        *reinterpret_cast<short*>(lds + 16384 + ((row*512 + col*2) ^ ((row&7)<<4)))
            = f2bf(fac[mt][nt][j]);
      }
  __syncthreads();

  // ---- heads GEMM: H2 = relu(final @ hw1t + b), wave owns cols [64w,64w+64) ----
  f32x4 hac[2][4];
  #pragma unroll
  for (int mt=0; mt<2; ++mt)
    #pragma unroll
    for (int nt=0; nt<4; ++nt) hac[mt][nt] = (f32x4){0,0,0,0};
  #pragma unroll
  for (int ks=0; ks<8; ++ks){
    short8 a0 = *reinterpret_cast<short8*>(lds + 16384 + (((lm   )*512 + (ks*32+kb)*2) ^ ((lm&7)<<4)));
    short8 a1 = *reinterpret_cast<short8*>(lds + 16384 + (((16+lm)*512 + (ks*32+kb)*2) ^ ((lm&7)<<4)));
    #pragma unroll
    for (int nt=0; nt<4; ++nt){
      short8 b = *reinterpret_cast<const short8*>(hw1t + (wv*64+nt*16+lm)*256 + ks*32 + kb);
      hac[0][nt] = MFMA16(a0, b, hac[0][nt]);
      hac[1][nt] = MFMA16(a1, b, hac[1][nt]);
    }
  }
  #pragma unroll
  for (int nt=0; nt<4; ++nt){
    int oc = wv*64 + nt*16 + lm;
    float bv = (oc < 128) ? val_b1[oc] : pol_b1[oc-128];
    #pragma unroll
    for (int mt=0; mt<2; ++mt)
      #pragma unroll
      for (int j=0; j<4; ++j){
        int row = mt*16 + grp*4 + j;
        *reinterpret_cast<short*>(lds + ((row*512 + oc*2) ^ ((row&7)<<4)))
            = f2bf(fmaxf(hac[mt][nt][j] + bv, 0.f));
      }
  }
  __syncthreads();

  // ---- projections ----
  {
    int a = tid >> 3, act = tid & 7;
    float s = pol_b2[act];
    #pragma unroll
    for (int i=0; i<16; ++i){
      short8 v = *reinterpret_cast<short8*>(lds + ((a*512 + (128 + i*8)*2) ^ ((a&7)<<4)));
      short8 w = *reinterpret_cast<const short8*>(pw2t + act*128 + i*8);
      #pragma unroll
      for (int e=0; e<8; ++e) s += bf2f(v[e]) * bf2f(w[e]);
    }
    dout[B_TOT + (size_t)(gb + a)*8 + act] = s;
  }
  if (tid < 64){
    int a = tid >> 1, hf = tid & 1;
    float s = 0.f;
    #pragma unroll
    for (int i=0; i<8; ++i){
      short8 v = *reinterpret_cast<short8*>(lds + ((a*512 + (hf*64 + i*8)*2) ^ ((a&7)<<4)));
      short8 w = *reinterpret_cast<const short8*>(vw2 + hf*64 + i*8);
      #pragma unroll
      for (int e=0; e<8; ++e) s += bf2f(v[e]) * bf2f(w[e]);
    }
    s += __shfl_xor(s, 1);
    if (!hf) dout[gb + a] = s + val_b2[0];
  }
}

extern "C" void kernel_launch(void* const* d_in, const int* in_sizes, int n_in,
                              void* d_out, int out_size, void* d_ws, size_t ws_size,
                              hipStream_t stream) {
  (void)in_sizes; (void)n_in; (void)out_size; (void)ws_size;
  const float* obs    = (const float*)d_in[0];
  const float* nobs   = (const float*)d_in[1];
  const int*   adj    = (const int*)  d_in[2];
  const float* enc_w1 = (const float*)d_in[3];
  const float* enc_b1 = (const float*)d_in[4];
  const float* enc_w2 = (const float*)d_in[5];
  const float* enc_b2 = (const float*)d_in[6];
  const float* gat_w  = (const float*)d_in[7];
  const float* gat_a  = (const float*)d_in[8];
  const float* val_w1 = (const float*)d_in[9];
  const float* val_b1 = (const float*)d_in[10];
  const float* val_w2 = (const float*)d_in[11];
  const float* val_b2 = (const float*)d_in[12];
  const float* pol_w1 = (const float*)d_in[13];
  const float* pol_b1 = (const float*)d_in[14];
  const float* pol_w2 = (const float*)d_in[15];
  const float* pol_b2 = (const float*)d_in[16];

  unsigned short* wt    = (unsigned short*)d_ws;
  float*          cvec  = (float*)((char*)d_ws + CVEC_BYTE);
  unsigned short* mixws = (unsigned short*)((char*)d_ws + MIX_BYTE);

  prep_weights2<<<(PREP_TOT + 255)/256, 256, 0, stream>>>(
      enc_w1, enc_w2, gat_w, gat_a, val_w1, pol_w1, pol_w2, val_w2, wt, cvec);

  enc_gat<<<B_TOT/16, 256, 0, stream>>>(
      obs, nobs, adj, enc_b1, enc_b2, wt, cvec, mixws);

  tail_k<<<B_TOT/32, 256, 0, stream>>>(
      mixws, wt, val_b1, val_b2, pol_b1, pol_b2, (float*)d_out);
}